// Round 9
// baseline (170.383 us; speedup 1.0000x reference)
//
#include <hip/hip_runtime.h>
#include <hip/hip_fp16.h>
#include <stdint.h>

#define NQ   300
#define CDIM 256
#define NH   8
#define HD   32
#define HWK  1024
#define HIDD 512

typedef __attribute__((ext_vector_type(8))) _Float16 f16x8;
typedef __attribute__((ext_vector_type(2))) _Float16 h2v;
typedef __attribute__((ext_vector_type(4))) float f32x4;

// ---- ws byte offsets ----
#define QB_OFF   0          // 300*256 f16 [q][c], scale folded
#define KB_OFF   153600     // 8*1024*32 f16 [h][k][d]
#define VT_OFF   677888     // [256 ch][1024 k] f16
#define PO_OFF   1202176    // [32 sl][300 q][256 c] f32 partial O (unnormalized)
#define PL_OFF   11032576   // [32 sl][300 q][8 h] f32 partial exp-sums
#define OB_OFF   11339776   // [300 q][256 c] f32 combined+normalized attn out

__device__ __forceinline__ short f16b(float x){
  _Float16 h = (_Float16)x;           // v_cvt_f16_f32 (RNE)
  return __builtin_bit_cast(short, h);
}

__device__ __forceinline__ h2v cvt2h(float a, float b){
  auto r = __builtin_amdgcn_cvt_pkrtz(a, b);
  return __builtin_bit_cast(h2v, r);
}

__device__ __forceinline__ uint32_t pk_f16(float a, float b){
  auto r = __builtin_amdgcn_cvt_pkrtz(a, b);
  return __builtin_bit_cast(uint32_t, r);
}

// ---------------- generic projection GEMM ----------------
// mode 0: q -> QB f16 (scaled); 1: k -> KB [h][k][d]; 2: v -> VT transposed;
// mode 3 (final): plain GEMM of ob with Wo -> d_out
__global__ __launch_bounds__(256) void proj_kernel(
    const float* __restrict__ rq, const float* __restrict__ qp,
    const float* __restrict__ rs, const float* __restrict__ spe,
    const float* __restrict__ Wq, const float* __restrict__ bq,
    const float* __restrict__ Wk, const float* __restrict__ bk,
    const float* __restrict__ Wv, const float* __restrict__ bv,
    const float* __restrict__ Wo, const float* __restrict__ bo,
    char* __restrict__ ws, float* __restrict__ dout, int final_mode)
{
  int bxid = blockIdx.x;
  int tile = bxid >> 1, half = bxid & 1;
  const float *in1, *in2, *W, *bias;
  int r0, M, mode;
  if (final_mode){
    in1 = (const float*)(ws + OB_OFF); in2 = nullptr; W = Wo; bias = bo;
    r0 = tile*16; M = NQ; mode = 3;
  } else if (tile < 19){
    in1 = rq; in2 = qp; W = Wq; bias = bq; r0 = tile*16; M = NQ; mode = 0;
  } else if (tile < 83){
    in1 = rs; in2 = spe; W = Wk; bias = bk; r0 = (tile-19)*16; M = HWK; mode = 1;
  } else {
    in1 = rs; in2 = spe; W = Wv; bias = bv; r0 = (tile-83)*16; M = HWK; mode = 2;
  }
  __shared__ __align__(16) float At[32][20];
  __shared__ float Wl[32][129];
  int tid = threadIdx.x;
  int n_loc = tid & 127;
  int rg = tid >> 7;
  int n = half*128 + n_loc;
  float acc[8];
  float bv_ = bias[n];
  #pragma unroll
  for (int i=0;i<8;i++) acc[i] = bv_;

  for (int c0 = 0; c0 < CDIM; c0 += 32){
    __syncthreads();
    for (int e = tid; e < 512; e += 256){
      int r = e >> 5, c = e & 31;
      int gr = r0 + r; if (gr >= M) gr = M - 1;
      float v = in1[gr*CDIM + c0 + c];
      if (in2) v += in2[gr*CDIM + c0 + c];
      At[c][r] = v;
    }
    for (int e = tid; e < 4096; e += 256){
      int c = e & 31, nn = e >> 5;
      Wl[c][nn] = W[(half*128 + nn)*CDIM + c0 + c];
    }
    __syncthreads();
    #pragma unroll
    for (int c = 0; c < 32; c++){
      float w = Wl[c][n_loc];
      const float4* ap = (const float4*)&At[c][rg*8];
      float4 a0 = ap[0], a1 = ap[1];
      acc[0] = fmaf(a0.x, w, acc[0]);
      acc[1] = fmaf(a0.y, w, acc[1]);
      acc[2] = fmaf(a0.z, w, acc[2]);
      acc[3] = fmaf(a0.w, w, acc[3]);
      acc[4] = fmaf(a1.x, w, acc[4]);
      acc[5] = fmaf(a1.y, w, acc[5]);
      acc[6] = fmaf(a1.z, w, acc[6]);
      acc[7] = fmaf(a1.w, w, acc[7]);
    }
  }

  if (mode == 0){
    short* qb = (short*)(ws + QB_OFF);
    const float s = 0.17677669529663687f;  // 1/sqrt(32)
    #pragma unroll
    for (int i=0;i<8;i++){
      int gr = r0 + rg*8 + i;
      if (gr < M) qb[gr*CDIM + n] = f16b(acc[i]*s);
    }
  } else if (mode == 1){
    short* kb = (short*)(ws + KB_OFF);
    int h = n >> 5, d = n & 31;
    #pragma unroll
    for (int i=0;i<8;i++){
      int gr = r0 + rg*8 + i;
      if (gr < M) kb[((size_t)h*HWK + gr)*HD + d] = f16b(acc[i]);
    }
  } else if (mode == 2){
    short* vt = (short*)(ws + VT_OFF);
    uint32_t p[4];
    #pragma unroll
    for (int i=0;i<4;i++) p[i] = pk_f16(acc[2*i], acc[2*i+1]);
    *(uint4*)(vt + n*HWK + r0 + rg*8) = make_uint4(p[0], p[1], p[2], p[3]);
  } else {
    #pragma unroll
    for (int i=0;i<8;i++){
      int gr = r0 + rg*8 + i;
      if (gr < M) dout[gr*CDIM + n] = acc[i];
    }
  }
}

// ---------------- fused: logits + on-the-fly CPB (packed f16) + exp + partial PV ----------------
// grid = 2400: q = bid>>3, kr = bid&7 (128 k). 4 waves; wave owns one ky-row (32 k).
// ONE barrier (after staging). Each wave writes its own global slice sl = kr*4+wave;
// no inter-wave combine, no second barrier.
__global__ __launch_bounds__(256, 6) void fused_kernel(
    const float* __restrict__ refp, const float* __restrict__ W1,
    const float* __restrict__ b1, const float* __restrict__ W2,
    const short* __restrict__ qb, const short* __restrict__ kb,
    const short* __restrict__ vt, float* __restrict__ po,
    float* __restrict__ pl)
{
  int bid = blockIdx.x;
  int q = bid >> 3, kr = bid & 7;
  int tid = threadIdx.x, wave = tid >> 6, lane = tid & 63;
  int n = lane & 15, qd = lane >> 4;

  __shared__ __align__(16) _Float16 nwx[HIDD];      // -wx
  __shared__ __align__(16) _Float16 c1s[4][HIDD];   // a - wy*ky, per wave-row
  __shared__ __align__(16) _Float16 w2l[NH][520];   // W2 f16
  __shared__ __align__(16) _Float16 pb[NH][136];    // this block's 128 k, f16 exp

  // stage nwx, c1 rows (f16), W2 (f16)
  float rx = refp[2*q], ry = refp[2*q+1];
  {
    int f0 = tid * 2;                                   // f-pair
    float4 w = *(const float4*)(W1 + 2*f0);             // wx0,wy0,wx1,wy1
    float2 bb = *(const float2*)(b1 + f0);
    float a0 = fmaf(w.x, rx, fmaf(w.y, ry, bb.x));
    float a1 = fmaf(w.z, rx, fmaf(w.w, ry, bb.y));
    *(h2v*)&nwx[f0] = cvt2h(-w.x, -w.z);
    #pragma unroll
    for (int r = 0; r < 4; r++){
      float ky = ((float)(kr*4 + r) + 0.5f) * (1.0f/32.0f);
      float c0 = fmaf(-w.y, ky, a0);
      float c1 = fmaf(-w.w, ky, a1);
      *(h2v*)&c1s[r][f0] = cvt2h(c0, c1);
    }
  }
  for (int e = tid; e < 2048; e += 256){
    int r = e >> 8, j = e & 255;
    float2 x = *(const float2*)(W2 + r*HIDD + 2*j);
    *(h2v*)&w2l[r][2*j] = cvt2h(x.x, x.y);
  }
  // per-head column-masked q fragments (f16); live range ends after phase 1
  f16x8 qfrag;
  if (n < NH) qfrag = *(const f16x8*)(qb + q*CDIM + n*HD + qd*8);
  else { f16x8 z = {0,0,0,0,0,0,0,0}; qfrag = z; }
  f16x8 qm[NH];
  #pragma unroll
  for (int h = 0; h < NH; h++){
    f16x8 z = {0,0,0,0,0,0,0,0};
    qm[h] = (n == h) ? qfrag : z;
  }
  __syncthreads();

  const int kyrow = kr*4 + wave;          // global ky row (0..31)
  const int kbase = kyrow * 32;           // global k base of this wave
  const int sl = kyrow;                   // output slice

  // ---- phase 1: logits -> acc registers, D[row=k-local][col=h] ----
  f32x4 acc[2];
  #pragma unroll
  for (int t = 0; t < 2; t++){
    int k0 = kbase + t*16;
    f32x4 d = {0.f,0.f,0.f,0.f};
    #pragma unroll
    for (int h = 0; h < NH; h++){
      f16x8 af = *(const f16x8*)(kb + ((size_t)h*HWK + k0 + n)*HD + qd*8);
      d = __builtin_amdgcn_mfma_f32_16x16x32_f16(af, qm[h], d, 0, 0, 0);
    }
    acc[t] = d;
  }

  // ---- phase 2: acc += relu(c1 - wx*kx) @ W2^T, packed f16 ----
  _Float16 kxAh = (_Float16)(((float)n + 0.5f) * (1.0f/32.0f));
  _Float16 kxBh = (_Float16)(((float)n + 16.5f) * (1.0f/32.0f));
  f16x8 kxA8, kxB8, z8;
  #pragma unroll
  for (int j = 0; j < 8; j++){ kxA8[j] = kxAh; kxB8[j] = kxBh; z8[j] = (_Float16)0.f; }
  const _Float16* c1r = &c1s[wave][0];
  #pragma unroll 4
  for (int kc = 0; kc < 16; kc++){
    int f0 = kc*32 + qd*8;                      // f index of this lane's 8 f
    f16x8 c1v = *(const f16x8*)(c1r + f0);
    f16x8 wxv = *(const f16x8*)(&nwx[f0]);
    f16x8 bfr = *(const f16x8*)(&w2l[n & 7][f0]);
    #pragma unroll
    for (int t = 0; t < 2; t++){
      f16x8 kx8 = t ? kxB8 : kxA8;
      f16x8 e = __builtin_elementwise_max(wxv * kx8 + c1v, z8);  // pk_fma + pk_max
      acc[t] = __builtin_amdgcn_mfma_f32_16x16x32_f16(e, bfr, acc[t], 0, 0, 0);
    }
  }

  // ---- phase 3: exp (no max-subtract; scores O(+-5)), pb f16, l partial ----
  float lacc = 0.f;
  #pragma unroll
  for (int t = 0; t < 2; t++){
    float e0 = __expf(acc[t][0]);
    float e1 = __expf(acc[t][1]);
    float e2 = __expf(acc[t][2]);
    float e3 = __expf(acc[t][3]);
    if (n < NH){
      uint2 p2;
      p2.x = pk_f16(e0, e1);
      p2.y = pk_f16(e2, e3);
      *(uint2*)&pb[n][wave*32 + t*16 + qd*4] = p2;
    }
    float s = e0 + e1 + e2 + e3;
    s += __shfl_xor(s, 16);
    s += __shfl_xor(s, 32);
    lacc += s;
  }
  if (lane < NH) pl[((size_t)sl*NQ + q)*NH + lane] = lacc;

  // ---- phase 4: partial PV over this wave's 32 k (same-wave pb reads), direct global write ----
  float* porow = po + ((size_t)sl*NQ + q)*CDIM;
  #pragma unroll
  for (int h = 0; h < NH; h++){
    int kl = wave*32 + qd*8;           // block-local k
    f16x8 pa = *(const f16x8*)&pb[h][kl];
    f16x8 v0 = *(const f16x8*)(vt + ((size_t)(h*HD +      n))*HWK + kr*128 + kl);
    f16x8 v1 = *(const f16x8*)(vt + ((size_t)(h*HD + 16 + n))*HWK + kr*128 + kl);
    f32x4 o0 = {0.f,0.f,0.f,0.f}, o1 = {0.f,0.f,0.f,0.f};
    o0 = __builtin_amdgcn_mfma_f32_16x16x32_f16(pa, v0, o0, 0, 0, 0);
    o1 = __builtin_amdgcn_mfma_f32_16x16x32_f16(pa, v1, o1, 0, 0, 0);
    if (qd == 0){
      porow[h*HD +      n] = o0[0];
      porow[h*HD + 16 + n] = o1[0];
    }
  }
}

// ---------------- combine: sum 32 slices, normalize -> ob ----------------
__global__ __launch_bounds__(256) void comb_kernel(
    const float* __restrict__ po, const float* __restrict__ pl,
    float* __restrict__ ob)
{
  int q = blockIdx.x, tid = threadIdx.x;
  __shared__ float linv[NH];
  if (tid < NH){
    float s = 0.f;
    #pragma unroll 8
    for (int p = 0; p < 32; p++) s += pl[((size_t)p*NQ + q)*NH + tid];
    linv[tid] = 1.0f / s;
  }
  __syncthreads();
  float v = 0.f;
  #pragma unroll 8
  for (int p = 0; p < 32; p++) v += po[((size_t)p*NQ + q)*CDIM + tid];
  ob[q*CDIM + tid] = v * linv[tid >> 5];
}

extern "C" void kernel_launch(void* const* d_in, const int* in_sizes, int n_in,
                              void* d_out, int out_size, void* d_ws, size_t ws_size,
                              hipStream_t stream)
{
  const float* rq  = (const float*)d_in[0];
  const float* qp  = (const float*)d_in[1];
  const float* rp  = (const float*)d_in[2];
  const float* rs  = (const float*)d_in[3];
  const float* spe = (const float*)d_in[4];
  const float* Wq  = (const float*)d_in[5];
  const float* bq  = (const float*)d_in[6];
  const float* Wk  = (const float*)d_in[7];
  const float* bk  = (const float*)d_in[8];
  const float* Wv  = (const float*)d_in[9];
  const float* bv  = (const float*)d_in[10];
  const float* Wo  = (const float*)d_in[11];
  const float* bo  = (const float*)d_in[12];
  const float* W1  = (const float*)d_in[13];
  const float* b1  = (const float*)d_in[14];
  const float* W2  = (const float*)d_in[15];
  char* ws = (char*)d_ws;
  float* dout = (float*)d_out;

  proj_kernel<<<294, 256, 0, stream>>>(rq, qp, rs, spe, Wq, bq, Wk, bk,
      Wv, bv, Wo, bo, ws, dout, 0);
  fused_kernel<<<2400, 256, 0, stream>>>(rp, W1, b1, W2,
      (const short*)(ws + QB_OFF), (const short*)(ws + KB_OFF),
      (const short*)(ws + VT_OFF), (float*)(ws + PO_OFF),
      (float*)(ws + PL_OFF));
  comb_kernel<<<300, 256, 0, stream>>>((const float*)(ws + PO_OFF),
      (const float*)(ws + PL_OFF), (float*)(ws + OB_OFF));
  proj_kernel<<<38, 256, 0, stream>>>(rq, qp, rs, spe, Wq, bq, Wk, bk,
      Wv, bv, Wo, bo, ws, dout, 1);
}

// Round 10
// 167.070 us; speedup vs baseline: 1.0198x; 1.0198x over previous
//
#include <hip/hip_runtime.h>
#include <hip/hip_fp16.h>
#include <stdint.h>

#define NQ   300
#define CDIM 256
#define NH   8
#define HD   32
#define HWK  1024
#define HIDD 512

typedef __attribute__((ext_vector_type(8))) _Float16 f16x8;
typedef __attribute__((ext_vector_type(2))) _Float16 h2v;
typedef __attribute__((ext_vector_type(4))) float f32x4;

// ---- ws byte offsets ----
#define QB_OFF   0          // 300*256 f16 [q][c], scale folded
#define KB_OFF   153600     // 8*1024*32 f16 [h][k][d]
#define VT_OFF   677888     // [256 ch][1024 k] f16
#define PO_OFF   1202176    // [8 kr][300 q][256 c] f32 partial O (unnormalized)
#define PL_OFF   3659776    // [8 kr][300 q][8 h] f32 partial exp-sums
#define A16_OFF  3736576    // [300][512] f16  a(q,f)
#define NX_OFF   4043776    // [512] f16 -wx
#define NY_OFF   4044800    // [512] f16 -wy
#define W2_OFF   4045824    // [8][512] f16 W2

__device__ __forceinline__ short f16b(float x){
  _Float16 h = (_Float16)x;
  return __builtin_bit_cast(short, h);
}

__device__ __forceinline__ uint32_t pk_f16(float a, float b){
  auto r = __builtin_amdgcn_cvt_pkrtz(a, b);
  return __builtin_bit_cast(uint32_t, r);
}

// ---------------- prep: f16 tables ----------------
__global__ __launch_bounds__(256) void prep_kernel(
    const float* __restrict__ refp, const float* __restrict__ W1,
    const float* __restrict__ b1, const float* __restrict__ W2,
    short* __restrict__ a16, short* __restrict__ nx16,
    short* __restrict__ ny16, short* __restrict__ w216)
{
  int idx = blockIdx.x * 256 + threadIdx.x;
  if (idx < NQ*HIDD){
    int q = idx >> 9, f = idx & 511;
    float2 w = ((const float2*)W1)[f];
    float a = fmaf(w.x, refp[2*q], fmaf(w.y, refp[2*q+1], b1[f]));
    a16[idx] = f16b(a);
  } else {
    int j = idx - NQ*HIDD;
    if (j < HIDD){
      float2 w = ((const float2*)W1)[j];
      nx16[j] = f16b(-w.x);
      ny16[j] = f16b(-w.y);
    } else if (j < HIDD + NH*HIDD){
      int e = j - HIDD;
      w216[e] = f16b(W2[e]);
    }
  }
}

// ---------------- generic projection GEMM ----------------
// mode 0: q -> QB f16 (scaled); 1: k -> KB [h][k][d]; 2: v -> VT transposed;
// mode 3 (final): A = sum of 8 PV partials * 1/sum(l), GEMM with Wo -> d_out
__global__ __launch_bounds__(256) void proj_kernel(
    const float* __restrict__ rq, const float* __restrict__ qp,
    const float* __restrict__ rs, const float* __restrict__ spe,
    const float* __restrict__ Wq, const float* __restrict__ bq,
    const float* __restrict__ Wk, const float* __restrict__ bk,
    const float* __restrict__ Wv, const float* __restrict__ bv,
    const float* __restrict__ Wo, const float* __restrict__ bo,
    char* __restrict__ ws, float* __restrict__ dout, int final_mode)
{
  int bxid = blockIdx.x;
  int tile = bxid >> 1, half = bxid & 1;
  const float *in1, *in2, *W, *bias;
  int r0, M, mode;
  const float* po = (const float*)(ws + PO_OFF);
  const float* pl = (const float*)(ws + PL_OFF);
  if (final_mode){
    in1 = po; in2 = nullptr; W = Wo; bias = bo;
    r0 = tile*16; M = NQ; mode = 3;
  } else if (tile < 19){
    in1 = rq; in2 = qp; W = Wq; bias = bq; r0 = tile*16; M = NQ; mode = 0;
  } else if (tile < 83){
    in1 = rs; in2 = spe; W = Wk; bias = bk; r0 = (tile-19)*16; M = HWK; mode = 1;
  } else {
    in1 = rs; in2 = spe; W = Wv; bias = bv; r0 = (tile-83)*16; M = HWK; mode = 2;
  }
  __shared__ __align__(16) float At[32][20];
  __shared__ float Wl[32][129];
  __shared__ float linv[16][8];
  int tid = threadIdx.x;
  int n_loc = tid & 127;
  int rg = tid >> 7;
  int n = half*128 + n_loc;
  float acc[8];
  float bv_ = bias[n];
  #pragma unroll
  for (int i=0;i<8;i++) acc[i] = bv_;

  if (mode == 3 && tid < 128){
    int r = tid >> 3, hh = tid & 7;
    int gr = r0 + r; if (gr >= M) gr = M - 1;
    float s = 0.f;
    #pragma unroll
    for (int p = 0; p < 8; p++) s += pl[((size_t)p*NQ+gr)*NH+hh];
    linv[r][hh] = 1.0f / s;
  }

  for (int c0 = 0; c0 < CDIM; c0 += 32){
    __syncthreads();
    for (int e = tid; e < 512; e += 256){
      int r = e >> 5, c = e & 31;
      int gr = r0 + r; if (gr >= M) gr = M - 1;
      float v;
      if (mode == 3){
        int cc = c0 + c;
        v = 0.f;
        #pragma unroll
        for (int p = 0; p < 8; p++) v += po[(size_t)(p*NQ+gr)*CDIM + cc];
        v *= linv[r][c0 >> 5];
      } else {
        v = in1[gr*CDIM + c0 + c];
        if (in2) v += in2[gr*CDIM + c0 + c];
      }
      At[c][r] = v;
    }
    for (int e = tid; e < 4096; e += 256){
      int c = e & 31, nn = e >> 5;
      Wl[c][nn] = W[(half*128 + nn)*CDIM + c0 + c];
    }
    __syncthreads();
    #pragma unroll
    for (int c = 0; c < 32; c++){
      float w = Wl[c][n_loc];
      const float4* ap = (const float4*)&At[c][rg*8];
      float4 a0 = ap[0], a1 = ap[1];
      acc[0] = fmaf(a0.x, w, acc[0]);
      acc[1] = fmaf(a0.y, w, acc[1]);
      acc[2] = fmaf(a0.z, w, acc[2]);
      acc[3] = fmaf(a0.w, w, acc[3]);
      acc[4] = fmaf(a1.x, w, acc[4]);
      acc[5] = fmaf(a1.y, w, acc[5]);
      acc[6] = fmaf(a1.z, w, acc[6]);
      acc[7] = fmaf(a1.w, w, acc[7]);
    }
  }

  if (mode == 0){
    short* qb = (short*)(ws + QB_OFF);
    const float s = 0.17677669529663687f;  // 1/sqrt(32)
    #pragma unroll
    for (int i=0;i<8;i++){
      int gr = r0 + rg*8 + i;
      if (gr < M) qb[gr*CDIM + n] = f16b(acc[i]*s);
    }
  } else if (mode == 1){
    short* kb = (short*)(ws + KB_OFF);
    int h = n >> 5, d = n & 31;
    #pragma unroll
    for (int i=0;i<8;i++){
      int gr = r0 + rg*8 + i;
      if (gr < M) kb[((size_t)h*HWK + gr)*HD + d] = f16b(acc[i]);
    }
  } else if (mode == 2){
    short* vt = (short*)(ws + VT_OFF);
    uint32_t p[4];
    #pragma unroll
    for (int i=0;i<4;i++) p[i] = pk_f16(acc[2*i], acc[2*i+1]);
    *(uint4*)(vt + n*HWK + r0 + rg*8) = make_uint4(p[0], p[1], p[2], p[3]);
  } else {
    #pragma unroll
    for (int i=0;i<8;i++){
      int gr = r0 + rg*8 + i;
      if (gr < M) dout[gr*CDIM + n] = acc[i];
    }
  }
}

// ---------------- fused: logits + on-the-fly CPB (packed f16) + exp + partial PV ----------------
// grid = 2400: q = bid>>3, kr = bid&7 (128 k). 4 waves; wave owns one ky-row (32 k).
// Staging now reads pre-converted f16 tables (prep_kernel): ~10 KB, no cvts.
__global__ __launch_bounds__(256, 5) void fused_kernel(
    const short* __restrict__ a16, const short* __restrict__ nx16,
    const short* __restrict__ ny16, const short* __restrict__ w216,
    const short* __restrict__ qb, const short* __restrict__ kb,
    const short* __restrict__ vt, float* __restrict__ po,
    float* __restrict__ pl)
{
  int bid = blockIdx.x;
  int q = bid >> 3, kr = bid & 7;
  int tid = threadIdx.x, wave = tid >> 6, lane = tid & 63;
  int n = lane & 15, qd = lane >> 4;

  __shared__ __align__(16) _Float16 nwx[HIDD];      // -wx
  __shared__ __align__(16) _Float16 c1s[4][HIDD];   // a - wy*ky, per wave-row
  __shared__ __align__(16) _Float16 w2l[NH][520];   // W2 f16
  __shared__ __align__(16) _Float16 pb[NH][136];    // this block's 128 k, f16 exp
  __shared__ __align__(16) float part[4][NH][32];
  __shared__ float lsum[4][NH];

  // stage from f16 tables
  {
    int f0 = tid * 2;
    h2v a2 = *(const h2v*)(a16 + q*HIDD + f0);
    h2v ny2 = *(const h2v*)(ny16 + f0);
    h2v nx2 = *(const h2v*)(nx16 + f0);
    *(h2v*)&nwx[f0] = nx2;
    #pragma unroll
    for (int r = 0; r < 4; r++){
      _Float16 kyh = (_Float16)(((float)(kr*4 + r) + 0.5f) * (1.0f/32.0f));
      h2v ky2 = {kyh, kyh};
      *(h2v*)&c1s[r][f0] = ny2 * ky2 + a2;    // v_pk_fma_f16
    }
  }
  for (int e = tid; e < 512; e += 256){
    int r = e >> 6, c = e & 63;
    *(f16x8*)&w2l[r][c*8] = *(const f16x8*)(w216 + r*HIDD + c*8);
  }
  // per-head column-masked q fragments (f16); live range ends after phase 1
  f16x8 qfrag;
  if (n < NH) qfrag = *(const f16x8*)(qb + q*CDIM + n*HD + qd*8);
  else { f16x8 z = {0,0,0,0,0,0,0,0}; qfrag = z; }
  f16x8 qm[NH];
  #pragma unroll
  for (int h = 0; h < NH; h++){
    f16x8 z = {0,0,0,0,0,0,0,0};
    qm[h] = (n == h) ? qfrag : z;
  }
  __syncthreads();

  const int kyrow = kr*4 + wave;          // global ky row (0..31)
  const int kbase = kyrow * 32;           // global k base of this wave

  // ---- phase 1: logits -> acc registers, D[row=k-local][col=h] ----
  f32x4 acc[2];
  #pragma unroll
  for (int t = 0; t < 2; t++){
    int k0 = kbase + t*16;
    f32x4 d = {0.f,0.f,0.f,0.f};
    #pragma unroll
    for (int h = 0; h < NH; h++){
      f16x8 af = *(const f16x8*)(kb + ((size_t)h*HWK + k0 + n)*HD + qd*8);
      d = __builtin_amdgcn_mfma_f32_16x16x32_f16(af, qm[h], d, 0, 0, 0);
    }
    acc[t] = d;
  }

  // ---- phase 2: acc += relu(c1 - wx*kx) @ W2^T, packed f16 ----
  _Float16 kxAh = (_Float16)(((float)n + 0.5f) * (1.0f/32.0f));
  _Float16 kxBh = (_Float16)(((float)n + 16.5f) * (1.0f/32.0f));
  f16x8 kxA8, kxB8, z8;
  #pragma unroll
  for (int j = 0; j < 8; j++){ kxA8[j] = kxAh; kxB8[j] = kxBh; z8[j] = (_Float16)0.f; }
  const _Float16* c1r = &c1s[wave][0];
  #pragma unroll 4
  for (int kc = 0; kc < 16; kc++){
    int f0 = kc*32 + qd*8;                      // f index of this lane's 8 f
    f16x8 c1v = *(const f16x8*)(c1r + f0);
    f16x8 wxv = *(const f16x8*)(&nwx[f0]);
    f16x8 bfr = *(const f16x8*)(&w2l[n & 7][f0]);
    #pragma unroll
    for (int t = 0; t < 2; t++){
      f16x8 kx8 = t ? kxB8 : kxA8;
      f16x8 e = __builtin_elementwise_max(wxv * kx8 + c1v, z8);  // pk_fma + pk_max
      acc[t] = __builtin_amdgcn_mfma_f32_16x16x32_f16(e, bfr, acc[t], 0, 0, 0);
    }
  }

  // ---- phase 3: exp (no max-subtract; scores O(+-5)), pb f16, l partials ----
  float lacc = 0.f;
  #pragma unroll
  for (int t = 0; t < 2; t++){
    float e0 = __expf(acc[t][0]);
    float e1 = __expf(acc[t][1]);
    float e2 = __expf(acc[t][2]);
    float e3 = __expf(acc[t][3]);
    if (n < NH){
      uint2 p2;
      p2.x = pk_f16(e0, e1);
      p2.y = pk_f16(e2, e3);
      *(uint2*)&pb[n][wave*32 + t*16 + qd*4] = p2;
    }
    float s = e0 + e1 + e2 + e3;
    s += __shfl_xor(s, 16);
    s += __shfl_xor(s, 32);
    lacc += s;
  }
  if (lane < NH) lsum[wave][lane] = lacc;

  // ---- phase 4: partial PV over this wave's 32 k (same-wave pb reads) ----
  #pragma unroll
  for (int h = 0; h < NH; h++){
    int kl = wave*32 + qd*8;           // block-local k
    f16x8 pa = *(const f16x8*)&pb[h][kl];
    f16x8 v0 = *(const f16x8*)(vt + ((size_t)(h*HD +      n))*HWK + kr*128 + kl);
    f16x8 v1 = *(const f16x8*)(vt + ((size_t)(h*HD + 16 + n))*HWK + kr*128 + kl);
    f32x4 o0 = {0.f,0.f,0.f,0.f}, o1 = {0.f,0.f,0.f,0.f};
    o0 = __builtin_amdgcn_mfma_f32_16x16x32_f16(pa, v0, o0, 0, 0, 0);
    o1 = __builtin_amdgcn_mfma_f32_16x16x32_f16(pa, v1, o1, 0, 0, 0);
    if (qd == 0){
      part[wave][h][n]      = o0[0];
      part[wave][h][16 + n] = o1[0];
    }
  }
  __syncthreads();

  // ---- combine waves, write partials ----
  {
    int h = tid >> 5, d = tid & 31;
    float s = part[0][h][d] + part[1][h][d] + part[2][h][d] + part[3][h][d];
    po[((size_t)kr*NQ + q)*CDIM + tid] = s;
    if (tid < NH)
      pl[((size_t)kr*NQ + q)*NH + tid] =
          lsum[0][tid] + lsum[1][tid] + lsum[2][tid] + lsum[3][tid];
  }
}

extern "C" void kernel_launch(void* const* d_in, const int* in_sizes, int n_in,
                              void* d_out, int out_size, void* d_ws, size_t ws_size,
                              hipStream_t stream)
{
  const float* rq  = (const float*)d_in[0];
  const float* qp  = (const float*)d_in[1];
  const float* rp  = (const float*)d_in[2];
  const float* rs  = (const float*)d_in[3];
  const float* spe = (const float*)d_in[4];
  const float* Wq  = (const float*)d_in[5];
  const float* bq  = (const float*)d_in[6];
  const float* Wk  = (const float*)d_in[7];
  const float* bk  = (const float*)d_in[8];
  const float* Wv  = (const float*)d_in[9];
  const float* bv  = (const float*)d_in[10];
  const float* Wo  = (const float*)d_in[11];
  const float* bo  = (const float*)d_in[12];
  const float* W1  = (const float*)d_in[13];
  const float* b1  = (const float*)d_in[14];
  const float* W2  = (const float*)d_in[15];
  char* ws = (char*)d_ws;
  float* dout = (float*)d_out;

  prep_kernel<<<618, 256, 0, stream>>>(rp, W1, b1, W2,
      (short*)(ws + A16_OFF), (short*)(ws + NX_OFF),
      (short*)(ws + NY_OFF), (short*)(ws + W2_OFF));
  proj_kernel<<<294, 256, 0, stream>>>(rq, qp, rs, spe, Wq, bq, Wk, bk,
      Wv, bv, Wo, bo, ws, dout, 0);
  fused_kernel<<<2400, 256, 0, stream>>>((const short*)(ws + A16_OFF),
      (const short*)(ws + NX_OFF), (const short*)(ws + NY_OFF),
      (const short*)(ws + W2_OFF), (const short*)(ws + QB_OFF),
      (const short*)(ws + KB_OFF), (const short*)(ws + VT_OFF),
      (float*)(ws + PO_OFF), (float*)(ws + PL_OFF));
  proj_kernel<<<38, 256, 0, stream>>>(rq, qp, rs, spe, Wq, bq, Wk, bk,
      Wv, bv, Wo, bo, ws, dout, 1);
}